// Round 3
// baseline (51.229 us; speedup 1.0000x reference)
//
#include <hip/hip_runtime.h>

// N=8, L=2048, E=1024, V=512. Only l=L-1 feeds logits -> GEMV pipeline.
// R3: decouple the 64 MB token stream (scorepack: wave-per-row, peak BW)
// from the VALU-heavy weighted bit-sum (wsum: operates on 2 MB packed bits).
#define NB 8
#define LS 2048
#define ED 1024
#define VD 512
#define CH 32          // m-chunks
#define CM 64          // m per chunk
typedef unsigned long long u64;

__device__ inline float wave_reduce_sum(float v) {
    #pragma unroll
    for (int off = 32; off > 0; off >>= 1)
        v += __shfl_down(v, off, 64);
    return v;
}

// q_row[n,f] = Wa_b[f] + sum_e tokens[n,L-1,e] * Wa_w[f,e]; one wave per (n,f)
__global__ void k_qrow(const int* __restrict__ tokens, const float* __restrict__ Wa_w,
                       const float* __restrict__ Wa_b, float* __restrict__ q_row) {
    int wid  = blockIdx.x * (blockDim.x >> 6) + (threadIdx.x >> 6);
    int lane = threadIdx.x & 63;
    int n = wid >> 10;
    int f = wid & (ED - 1);
    const int*   xrow = tokens + ((size_t)n * LS + (LS - 1)) * ED;
    const float* wrow = Wa_w + (size_t)f * ED;
    float acc = 0.f;
    #pragma unroll
    for (int k = 0; k < ED; k += 256) {
        int idx = k + lane * 4;
        int4   t = *reinterpret_cast<const int4*>(xrow + idx);
        float4 w = *reinterpret_cast<const float4*>(wrow + idx);
        acc += (float)t.x * w.x + (float)t.y * w.y + (float)t.z * w.z + (float)t.w * w.w;
    }
    acc = wave_reduce_sum(acc);
    if (lane == 0) q_row[wid] = acc + Wa_b[f];
}

// scores[n,m] + packed bits. One wave per (n,m) row: reads 4 KB tokens,
// dots with q (L2-hot), ballots bits into pk[n][m][16] u64.
// Bit map: e = k + 4*lane + j  ->  word (k>>6)+j, bit `lane`.
__global__ void k_scorepack(const int* __restrict__ tokens, const float* __restrict__ q_row,
                            float* __restrict__ scores, u64* __restrict__ pk) {
    int wid  = blockIdx.x * (blockDim.x >> 6) + (threadIdx.x >> 6);
    int lane = threadIdx.x & 63;
    int n = wid >> 11;            // /LS
    int m = wid & (LS - 1);
    const int*   xrow = tokens + (size_t)wid * ED;
    const float* q    = q_row + n * ED;
    u64* pkrow = pk + (size_t)wid * 16;
    float acc = 0.f;
    #pragma unroll
    for (int k = 0; k < ED; k += 256) {
        int idx = k + lane * 4;
        int4   tv = *reinterpret_cast<const int4*>(xrow + idx);
        float4 qv = *reinterpret_cast<const float4*>(q + idx);
        u64 b0 = __ballot(tv.x != 0);
        u64 b1 = __ballot(tv.y != 0);
        u64 b2 = __ballot(tv.z != 0);
        u64 b3 = __ballot(tv.w != 0);
        u64 bb = b0;
        bb = (lane == 1) ? b1 : bb;
        bb = (lane == 2) ? b2 : bb;
        bb = (lane == 3) ? b3 : bb;
        if (lane < 4) pkrow[(k >> 6) + lane] = bb;
        acc += (float)tv.x * qv.x + (float)tv.y * qv.y
             + (float)tv.z * qv.z + (float)tv.w * qv.w;
    }
    acc = wave_reduce_sum(acc);
    if (lane == 0) scores[wid] = acc;
}

// Block per (n, chunk of 64 m): redundant softmax stats over the n's 2048
// scores (fixed-order reduce -> deterministic & identical across blocks),
// then weighted bit-sum from packed rows. partial[n][c][e].
__global__ __launch_bounds__(1024) void k_wsum(const float* __restrict__ scores,
                                               const u64* __restrict__ pk,
                                               float* __restrict__ partial) {
    int n = blockIdx.x >> 5;
    int c = blockIdx.x & (CH - 1);
    int t = threadIdx.x;
    __shared__ float red[1024];
    __shared__ float p_lds[CM];

    float s0 = scores[n * LS + t];
    float s1 = scores[n * LS + t + 1024];
    red[t] = fmaxf(s0, s1); __syncthreads();
    for (int off = 512; off > 0; off >>= 1) {
        if (t < off) red[t] = fmaxf(red[t], red[t + off]);
        __syncthreads();
    }
    float mu = red[0]; __syncthreads();
    red[t] = expf(s0 - mu) + expf(s1 - mu); __syncthreads();
    for (int off = 512; off > 0; off >>= 1) {
        if (t < off) red[t] += red[t + off];
        __syncthreads();
    }
    float invZ = 1.f / red[0];
    if (t < CM) p_lds[t] = expf(scores[n * LS + c * CM + t] - mu) * invZ;
    __syncthreads();

    // thread t == e; word ((e>>8)<<2)|(e&3), bit (e>>2)&63
    const u64* rows = pk + ((size_t)(n * LS + c * CM)) * 16;
    int w   = ((t >> 8) << 2) | (t & 3);
    int bit = (t >> 2) & 63;
    float acc = 0.f;
    #pragma unroll 8
    for (int m = 0; m < CM; ++m) {
        acc += ((rows[m * 16 + w] >> bit) & 1ull) ? p_lds[m] : 0.f;
    }
    partial[(size_t)blockIdx.x * ED + t] = acc;
}

// Block per (n, v-tile of 32): combine 32 chunk-partials into a_row (LDS),
// then GEMV against Wb_w + bias. 128 blocks of 1024.
__global__ __launch_bounds__(1024) void k_out(const float* __restrict__ partial,
                                              const float* __restrict__ Wb_w,
                                              const float* __restrict__ Wb_b,
                                              float* __restrict__ out) {
    int n  = blockIdx.x >> 4;
    int vt = blockIdx.x & 15;
    int t  = threadIdx.x;
    int wave = t >> 6, lane = t & 63;
    __shared__ float a_lds[ED];

    float acc = 0.f;
    #pragma unroll
    for (int c = 0; c < CH; ++c)
        acc += partial[((size_t)(n * CH + c)) * ED + t];
    a_lds[t] = acc; __syncthreads();

    #pragma unroll
    for (int i = 0; i < 2; ++i) {
        int v = vt * 32 + wave * 2 + i;
        const float* wr = Wb_w + (size_t)v * ED;
        float d = 0.f;
        #pragma unroll
        for (int k = 0; k < ED; k += 256) {
            int idx = k + lane * 4;
            float4 wv = *reinterpret_cast<const float4*>(wr + idx);
            float4 av = *reinterpret_cast<const float4*>(&a_lds[idx]);
            d += av.x * wv.x + av.y * wv.y + av.z * wv.z + av.w * wv.w;
        }
        d = wave_reduce_sum(d);
        if (lane == 0) out[n * VD + v] = d + Wb_b[v];
    }
}

extern "C" void kernel_launch(void* const* d_in, const int* in_sizes, int n_in,
                              void* d_out, int out_size, void* d_ws, size_t ws_size,
                              hipStream_t stream) {
    const int*   tokens = (const int*)  d_in[0];
    const float* Wa_w   = (const float*)d_in[1];
    const float* Wa_b   = (const float*)d_in[2];
    const float* Wb_w   = (const float*)d_in[3];
    const float* Wb_b   = (const float*)d_in[4];
    float* out = (float*)d_out;

    // ws layout: u64 pk first (8B-aligned), then floats
    u64*   pk      = (u64*)d_ws;                         // 8*2048*16 u64 = 2 MB
    float* q_row   = (float*)(pk + (size_t)NB * LS * 16);// 8192
    float* scores  = q_row + NB * ED;                    // 16384
    float* partial = scores + NB * LS;                   // 8*32*1024 = 262144

    // 1) q_row: 8192 waves -> 2048 blocks of 256
    k_qrow<<<dim3((NB * ED) / 4), dim3(256), 0, stream>>>(tokens, Wa_w, Wa_b, q_row);
    // 2) scores + bit-pack: 16384 waves -> 4096 blocks of 256 (the 64 MB stream)
    k_scorepack<<<dim3((NB * LS) / 4), dim3(256), 0, stream>>>(tokens, q_row, scores, pk);
    // 3) softmax + weighted bit-sum partials: 256 blocks of 1024
    k_wsum<<<dim3(NB * CH), dim3(1024), 0, stream>>>(scores, pk, partial);
    // 4) combine + output GEMV: 128 blocks of 1024
    k_out<<<dim3(NB * 16), dim3(1024), 0, stream>>>(partial, Wb_w, Wb_b, out);
}

// Round 4
// 31.610 us; speedup vs baseline: 1.6207x; 1.6207x over previous
//
#include <hip/hip_runtime.h>

// N=8, L=2048, E=1024, V=512. Only l=L-1 feeds logits -> GEMV pipeline.
// R4: back to the R2 fused-flash structure (tokens read once, bits packed in
// LDS during the score pass), with: 512x512 blocks (2/CU -> tail overlap),
// direct per-thread phase-3 accumulation (no LDS re-reduce), and the chunk
// combine folded into the output GEMV (3 kernels total).
#define NB 8
#define LS 2048
#define ED 1024
#define VD 512
#define CM 32           // m-rows per flash block
#define CH (LS / CM)    // 64 chunks
typedef unsigned long long u64;

__device__ inline float wave_reduce_sum(float v) {
    #pragma unroll
    for (int off = 32; off > 0; off >>= 1)
        v += __shfl_down(v, off, 64);
    return v;
}

// q_row[n,f] = Wa_b[f] + sum_e tokens[n,L-1,e] * Wa_w[f,e]; one wave per (n,f)
__global__ void k_qrow(const int* __restrict__ tokens, const float* __restrict__ Wa_w,
                       const float* __restrict__ Wa_b, float* __restrict__ q_row) {
    int wid  = blockIdx.x * (blockDim.x >> 6) + (threadIdx.x >> 6);
    int lane = threadIdx.x & 63;
    int n = wid >> 10;
    int f = wid & (ED - 1);
    const int*   xrow = tokens + ((size_t)n * LS + (LS - 1)) * ED;
    const float* wrow = Wa_w + (size_t)f * ED;
    float acc = 0.f;
    #pragma unroll
    for (int k = 0; k < ED; k += 256) {
        int idx = k + lane * 4;
        int4   t = *reinterpret_cast<const int4*>(xrow + idx);
        float4 w = *reinterpret_cast<const float4*>(wrow + idx);
        acc += (float)t.x * w.x + (float)t.y * w.y + (float)t.z * w.z + (float)t.w * w.w;
    }
    acc = wave_reduce_sum(acc);
    if (lane == 0) q_row[wid] = acc + Wa_b[f];
}

// Fused: one block (512 thr, 8 waves) per (n, chunk of 32 m).
// Phase 1: 8 waves x 4 rows: score dot + ballot-pack bits into LDS.
// Phase 2: chunk softmax stats (mu_c, z_c, unnormalized p_m).
// Phase 3: pa[n,c,e] = sum_m p_m * bit(m,e); thread t owns e=t and e=t+512.
__global__ __launch_bounds__(512) void k_flash(const int* __restrict__ tokens,
                                               const float* __restrict__ q_row,
                                               float* __restrict__ pa,
                                               float* __restrict__ mu_g,
                                               float* __restrict__ z_g) {
    int n = blockIdx.x >> 6;      // /CH
    int c = blockIdx.x & (CH - 1);
    int t = threadIdx.x;
    int wave = t >> 6, lane = t & 63;

    __shared__ u64   pk[CM][16];  // 4 KB packed bits
    __shared__ float s_lds[CM];
    __shared__ float p_lds[CM];

    const float* q = q_row + n * ED;

    // ---- phase 1: scores + bit-pack ----
    #pragma unroll
    for (int i = 0; i < 4; ++i) {
        int m = wave + 8 * i;
        const int* row = tokens + ((size_t)(n * LS + c * CM + m)) * ED;
        float acc = 0.f;
        #pragma unroll
        for (int k = 0; k < ED; k += 256) {
            int idx = k + lane * 4;
            int4   tv = *reinterpret_cast<const int4*>(row + idx);
            float4 qv = *reinterpret_cast<const float4*>(q + idx);
            u64 b0 = __ballot(tv.x != 0);
            u64 b1 = __ballot(tv.y != 0);
            u64 b2 = __ballot(tv.z != 0);
            u64 b3 = __ballot(tv.w != 0);
            if (lane == 0) {
                int wb = (k >> 8) * 4;   // e = k+4*lane+j -> word (e>>8)*4+(e&3), bit (e>>2)&63
                pk[m][wb + 0] = b0; pk[m][wb + 1] = b1;
                pk[m][wb + 2] = b2; pk[m][wb + 3] = b3;
            }
            acc += (float)tv.x * qv.x + (float)tv.y * qv.y
                 + (float)tv.z * qv.z + (float)tv.w * qv.w;
        }
        acc = wave_reduce_sum(acc);
        if (lane == 0) s_lds[m] = acc;
    }
    __syncthreads();

    // ---- phase 2: chunk softmax stats (wave 0; lanes 0..31 hold scores) ----
    if (wave == 0) {
        float s = (lane < CM) ? s_lds[lane] : -3.0e38f;
        float mx = s;
        #pragma unroll
        for (int off = 16; off > 0; off >>= 1) mx = fmaxf(mx, __shfl_xor(mx, off, 64));
        float p = (lane < CM) ? expf(s - mx) : 0.f;
        float z = p;
        #pragma unroll
        for (int off = 16; off > 0; off >>= 1) z += __shfl_xor(z, off, 64);
        if (lane < CM) p_lds[lane] = p;
        if (lane == 0) { mu_g[blockIdx.x] = mx; z_g[blockIdx.x] = z; }
    }
    __syncthreads();

    // ---- phase 3: weighted bit-sum; e0 = t, e1 = t + 512 (same bit, word+8) ----
    int w0  = ((t >> 8) << 2) | (t & 3);
    int bit = (t >> 2) & 63;
    float a0 = 0.f, a1 = 0.f;
    #pragma unroll 8
    for (int m = 0; m < CM; ++m) {
        float p  = p_lds[m];
        u64   lo = pk[m][w0];
        u64   hi = pk[m][w0 + 8];
        a0 += ((lo >> bit) & 1ull) ? p : 0.f;
        a1 += ((hi >> bit) & 1ull) ? p : 0.f;
    }
    float* par = pa + (size_t)blockIdx.x * ED;
    par[t]       = a0;
    par[t + 512] = a1;
}

// Combine + GEMV: block per (n, v-tile of 32). Wave 0 builds coef[c] =
// exp(mu_c - mu)/Z (CH==64 == one wave), all 1024 threads combine pa into
// a_lds, then 16 waves x 2 v each dot with Wb_w.
__global__ __launch_bounds__(1024) void k_out(const float* __restrict__ pa,
                                              const float* __restrict__ mu_g,
                                              const float* __restrict__ z_g,
                                              const float* __restrict__ Wb_w,
                                              const float* __restrict__ Wb_b,
                                              float* __restrict__ out) {
    int n  = blockIdx.x >> 4;
    int vt = blockIdx.x & 15;
    int t  = threadIdx.x;
    int wave = t >> 6, lane = t & 63;
    __shared__ float coef[CH];
    __shared__ float a_lds[ED];

    if (wave == 0) {
        float m_c = mu_g[n * CH + lane];
        float mx = m_c;
        #pragma unroll
        for (int off = 32; off > 0; off >>= 1) mx = fmaxf(mx, __shfl_xor(mx, off, 64));
        float cf = expf(m_c - mx);
        float zc = z_g[n * CH + lane] * cf;
        float Z = zc;
        #pragma unroll
        for (int off = 32; off > 0; off >>= 1) Z += __shfl_xor(Z, off, 64);
        coef[lane] = cf / Z;
    }
    __syncthreads();

    float acc = 0.f;
    #pragma unroll
    for (int ci = 0; ci < CH; ++ci)
        acc += coef[ci] * pa[((size_t)(n * CH + ci)) * ED + t];
    a_lds[t] = acc;
    __syncthreads();

    #pragma unroll
    for (int i = 0; i < 2; ++i) {
        int v = vt * 32 + wave * 2 + i;
        const float* wr = Wb_w + (size_t)v * ED;
        float d = 0.f;
        #pragma unroll
        for (int k = 0; k < ED; k += 256) {
            int idx = k + lane * 4;
            float4 wv = *reinterpret_cast<const float4*>(wr + idx);
            float4 av = *reinterpret_cast<const float4*>(&a_lds[idx]);
            d += av.x * wv.x + av.y * wv.y + av.z * wv.z + av.w * wv.w;
        }
        d = wave_reduce_sum(d);
        if (lane == 0) out[n * VD + v] = d + Wb_b[v];
    }
}

extern "C" void kernel_launch(void* const* d_in, const int* in_sizes, int n_in,
                              void* d_out, int out_size, void* d_ws, size_t ws_size,
                              hipStream_t stream) {
    const int*   tokens = (const int*)  d_in[0];
    const float* Wa_w   = (const float*)d_in[1];
    const float* Wa_b   = (const float*)d_in[2];
    const float* Wb_w   = (const float*)d_in[3];
    const float* Wb_b   = (const float*)d_in[4];
    float* out = (float*)d_out;

    float* ws    = (float*)d_ws;
    float* q_row = ws;                               // 8192
    float* pa    = q_row + NB * ED;                  // 8*64*1024 = 524288
    float* mu_g  = pa + (size_t)NB * CH * ED;        // 512
    float* z_g   = mu_g + NB * CH;                   // 512

    // 1) q_row: 8192 waves -> 2048 blocks of 256
    k_qrow<<<dim3((NB * ED) / 4), dim3(256), 0, stream>>>(tokens, Wa_w, Wa_b, q_row);
    // 2) fused scores+softmax+weighted-sum: 512 blocks of 512 (reads tokens ONCE)
    k_flash<<<dim3(NB * CH), dim3(512), 0, stream>>>(tokens, q_row, pa, mu_g, z_g);
    // 3) combine + output GEMV: 128 blocks of 1024
    k_out<<<dim3(NB * 16), dim3(1024), 0, stream>>>(pa, mu_g, z_g, Wb_w, Wb_b, out);
}